// Round 3
// baseline (1367.677 us; speedup 1.0000x reference)
//
#include <hip/hip_runtime.h>

#define B_ 32
#define C_ 256
#define CI_ 128
#define N_ 4096

typedef unsigned int u32;
typedef unsigned short u16;

__device__ __forceinline__ u16 f2bs(float f) {   // fp32 -> bf16 bits (RNE)
    union { float f; u32 u; } c; c.f = f;
    u32 u = c.u + 0x7FFFu + ((c.u >> 16) & 1u);
    return (u16)(u >> 16);
}
__device__ __forceinline__ float bs2f(u16 s) {   // bf16 bits -> fp32
    union { u32 u; float f; } c; c.u = ((u32)s) << 16; return c.f;
}

// ---------------------------------------------------------------------------
// K0: zero G (fp32 atomic accumulator). 2,097,152 floats = 524,288 float4.
// ---------------------------------------------------------------------------
__global__ __launch_bounds__(256) void zero_kernel(float* __restrict__ p) {
    int i = blockIdx.x * 256 + threadIdx.x;
    ((float4*)p)[i] = make_float4(0.f, 0.f, 0.f, 0.f);
}

// ---------------------------------------------------------------------------
// K1: row sums sx[b,t] = sum_n X[b,t,n]. grid (C, B), block 64 (one wave).
// ---------------------------------------------------------------------------
__global__ __launch_bounds__(64) void sx_kernel(
    const float* __restrict__ x, float* __restrict__ sx)
{
    const int t = blockIdx.x, b = blockIdx.y, lane = threadIdx.x;
    const float* row = x + ((size_t)(b * C_ + t)) * N_;
    float s = 0.f;
    for (int k = lane; k < N_; k += 64) s += row[k];
    #pragma unroll
    for (int off = 32; off > 0; off >>= 1) s += __shfl_down(s, off);
    if (lane == 0) sx[b * C_ + t] = s;
}

// ---------------------------------------------------------------------------
// K2: Gram G[b] = X_b · X_bᵀ (fp32 [256,256]/batch, atomicAdd over 4 n-chunks)
// grid (2,2,B*4), block (16,16), 8x8 per thread.
// ---------------------------------------------------------------------------
__global__ __launch_bounds__(256) void gram_kernel(
    const float* __restrict__ x, float* __restrict__ G)
{
    const int b = blockIdx.z >> 2, q = blockIdx.z & 3;
    const int i0 = blockIdx.y * 128, j0 = blockIdx.x * 128;
    const int tx = threadIdx.x, ty = threadIdx.y, tid = ty * 16 + tx;
    __shared__ float Xi[32][129], Xj[32][129];
    float acc[8][8] = {};
    for (int n0 = q * 1024; n0 < q * 1024 + 1024; n0 += 32) {
        for (int r = 0; r < 16; ++r) {
            int e = tid + 256 * r;
            int ii = e >> 5, kk = e & 31;
            Xi[kk][ii] = x[((size_t)(b * C_ + i0 + ii)) * N_ + n0 + kk];
            Xj[kk][ii] = x[((size_t)(b * C_ + j0 + ii)) * N_ + n0 + kk];
        }
        __syncthreads();
        for (int k = 0; k < 32; ++k) {
            float a[8], c[8];
            #pragma unroll
            for (int u = 0; u < 8; ++u) a[u] = Xi[k][ty * 8 + u];
            #pragma unroll
            for (int v = 0; v < 8; ++v) c[v] = Xj[k][tx * 8 + v];
            #pragma unroll
            for (int u = 0; u < 8; ++u)
                #pragma unroll
                for (int v = 0; v < 8; ++v) acc[u][v] += a[u] * c[v];
        }
        __syncthreads();
    }
    #pragma unroll
    for (int u = 0; u < 8; ++u)
        #pragma unroll
        for (int v = 0; v < 8; ++v)
            atomicAdd(&G[(size_t)b * 65536 + (size_t)(i0 + ty * 8 + u) * 256 + j0 + tx * 8 + v],
                      acc[u][v]);
}

// ---------------------------------------------------------------------------
// K3: A1[b] = Tw · G[b]  ([128,256] fp32). grid (2,B), block (16,16).
// ---------------------------------------------------------------------------
__global__ __launch_bounds__(256) void a1_kernel(
    const float* __restrict__ tw, const float* __restrict__ G,
    float* __restrict__ A1)
{
    const int b = blockIdx.y, u0 = blockIdx.x * 128;
    const int tx = threadIdx.x, ty = threadIdx.y, tid = ty * 16 + tx;
    __shared__ float Tws[32][129], Gs[32][129];
    float acc[8][8] = {};
    for (int t0 = 0; t0 < C_; t0 += 32) {
        for (int r = 0; r < 16; ++r) {
            int e = tid + 256 * r;
            int ii = e >> 5, tk = e & 31;
            Tws[tk][ii] = tw[ii * C_ + t0 + tk];
        }
        for (int r = 0; r < 16; ++r) {
            int e = tid + 256 * r;
            int tk = e >> 7, uu = e & 127;
            Gs[tk][uu] = G[(size_t)b * 65536 + (size_t)(t0 + tk) * 256 + u0 + uu];
        }
        __syncthreads();
        for (int k = 0; k < 32; ++k) {
            float a[8], c[8];
            #pragma unroll
            for (int u = 0; u < 8; ++u) a[u] = Tws[k][ty * 8 + u];
            #pragma unroll
            for (int v = 0; v < 8; ++v) c[v] = Gs[k][tx * 8 + v];
            #pragma unroll
            for (int u = 0; u < 8; ++u)
                #pragma unroll
                for (int v = 0; v < 8; ++v) acc[u][v] += a[u] * c[v];
        }
        __syncthreads();
    }
    #pragma unroll
    for (int u = 0; u < 8; ++u)
        #pragma unroll
        for (int v = 0; v < 8; ++v)
            A1[(size_t)b * 32768 + (size_t)(ty * 8 + u) * 256 + u0 + tx * 8 + v] = acc[u][v];
}

// ---------------------------------------------------------------------------
// K4: F = A1·Pwᵀ + t1·pbᵀ + tb·t2ᵀ + N·tb·pbᵀ, row-softmax -> fsm fp32.
// grid (B), block (16,16); 8x8 per thread; shfl row-reduce over 16 lanes.
// ---------------------------------------------------------------------------
__global__ __launch_bounds__(256) void f_kernel(
    const float* __restrict__ A1,
    const float* __restrict__ tw, const float* __restrict__ tb,
    const float* __restrict__ pw, const float* __restrict__ pb,
    const float* __restrict__ sx, float* __restrict__ fsm)
{
    const int b = blockIdx.x;
    const int tx = threadIdx.x, ty = threadIdx.y, tid = ty * 16 + tx;
    __shared__ float sxs[256], t12[256];
    __shared__ float As[32][129], Ps[32][129];
    sxs[tid] = sx[b * 256 + tid];
    __syncthreads();
    {   // t1[i] = Tw·sx ; t2[j] = Pw·sx
        float s = 0.f;
        if (tid < 128) {
            for (int t = 0; t < 256; ++t) s += tw[tid * 256 + t] * sxs[t];
        } else {
            int j = tid - 128;
            for (int t = 0; t < 256; ++t) s += pw[j * 256 + t] * sxs[t];
        }
        t12[tid] = s;
    }
    float acc[8][8] = {};
    for (int u0 = 0; u0 < C_; u0 += 32) {
        for (int r = 0; r < 16; ++r) {
            int e = tid + 256 * r;
            int ii = e >> 5, uk = e & 31;
            As[uk][ii] = A1[(size_t)b * 32768 + (size_t)ii * 256 + u0 + uk];
            Ps[uk][ii] = pw[ii * 256 + u0 + uk];
        }
        __syncthreads();
        for (int k = 0; k < 32; ++k) {
            float a[8], c[8];
            #pragma unroll
            for (int u = 0; u < 8; ++u) a[u] = As[k][ty * 8 + u];
            #pragma unroll
            for (int v = 0; v < 8; ++v) c[v] = Ps[k][tx * 8 + v];
            #pragma unroll
            for (int u = 0; u < 8; ++u)
                #pragma unroll
                for (int v = 0; v < 8; ++v) acc[u][v] += a[u] * c[v];
        }
        __syncthreads();
    }
    float tbv[8], pbv[8], t2v[8];
    #pragma unroll
    for (int u = 0; u < 8; ++u) tbv[u] = tb[ty * 8 + u];
    #pragma unroll
    for (int v = 0; v < 8; ++v) {
        int j = tx * 8 + v;
        pbv[v] = pb[j];
        t2v[v] = t12[128 + j];
    }
    #pragma unroll
    for (int u = 0; u < 8; ++u) {
        const int i = ty * 8 + u;
        float t1i = t12[i];
        float row[8];
        #pragma unroll
        for (int v = 0; v < 8; ++v)
            row[v] = acc[u][v] + t1i * pbv[v] + tbv[u] * (t2v[v] + 4096.0f * pbv[v]);
        float m = row[0];
        #pragma unroll
        for (int v = 1; v < 8; ++v) m = fmaxf(m, row[v]);
        m = fmaxf(m, __shfl_xor(m, 1));
        m = fmaxf(m, __shfl_xor(m, 2));
        m = fmaxf(m, __shfl_xor(m, 4));
        m = fmaxf(m, __shfl_xor(m, 8));
        float s = 0.f;
        #pragma unroll
        for (int v = 0; v < 8; ++v) s += __expf(row[v] - m);
        s += __shfl_xor(s, 1);
        s += __shfl_xor(s, 2);
        s += __shfl_xor(s, 4);
        s += __shfl_xor(s, 8);
        float inv = 1.0f / s;
        #pragma unroll
        for (int v = 0; v < 8; ++v)
            fsm[(size_t)b * 16384 + (size_t)i * 128 + tx * 8 + v] = __expf(row[v] - m) * inv;
    }
}

// ---------------------------------------------------------------------------
// K5: M[b] = f_smᵀ · Gw ([128 j,256 t] fp32, reuses A1 buffer);
//     rj[b,j] = f_smᵀ · gb. grid (2,B), block (16,16).
// ---------------------------------------------------------------------------
__global__ __launch_bounds__(256) void m_kernel(
    const float* __restrict__ fsm, const float* __restrict__ gw,
    const float* __restrict__ gb,
    float* __restrict__ M, float* __restrict__ rj)
{
    const int b = blockIdx.y, t0 = blockIdx.x * 128;
    const int tx = threadIdx.x, ty = threadIdx.y, tid = ty * 16 + tx;
    __shared__ float Fs[32][129], Gs[32][129];
    float acc[8][8] = {};
    for (int i0 = 0; i0 < CI_; i0 += 32) {
        for (int r = 0; r < 16; ++r) {
            int e = tid + 256 * r;
            int ik = e >> 7, jj = e & 127;
            Fs[ik][jj] = fsm[(size_t)b * 16384 + (size_t)(i0 + ik) * 128 + jj];
            Gs[ik][jj] = gw[(i0 + ik) * 256 + t0 + jj];
        }
        __syncthreads();
        for (int k = 0; k < 32; ++k) {
            float a[8], c[8];
            #pragma unroll
            for (int u = 0; u < 8; ++u) a[u] = Fs[k][ty * 8 + u];
            #pragma unroll
            for (int v = 0; v < 8; ++v) c[v] = Gs[k][tx * 8 + v];
            #pragma unroll
            for (int u = 0; u < 8; ++u)
                #pragma unroll
                for (int v = 0; v < 8; ++v) acc[u][v] += a[u] * c[v];
        }
        __syncthreads();
    }
    #pragma unroll
    for (int u = 0; u < 8; ++u)
        #pragma unroll
        for (int v = 0; v < 8; ++v)
            M[(size_t)b * 32768 + (size_t)(ty * 8 + u) * 256 + t0 + tx * 8 + v] = acc[u][v];
    if (blockIdx.x == 0 && tid < 128) {
        float s = 0.f;
        for (int i = 0; i < 128; ++i)
            s += fsm[(size_t)b * 16384 + (size_t)i * 128 + tid] * gb[i];
        rj[b * 128 + tid] = s;
    }
}

// ---------------------------------------------------------------------------
// K6 (fused y + out conv + residual):
//   Y2[c,p] = y[b, j=p&127, n=32c+(p>>7)] (torch permute+view identity)
//   out[b,o,p] = sum_c Ow[o,c]·Y2[c,p] + ob[o] + x[b,o,p]
// Block (b,q): p in [128q,128q+128). Phase 1: Z[j][c] = sum_t M[j,t]·X[t,32c+q]
// + rj[j] (bf16 in LDS). Phase 2: out-tile = Ow·Zᵀ + ob + x. No yt in HBM.
// grid (32 q, B), block (16,16).
// ---------------------------------------------------------------------------
__global__ __launch_bounds__(256) void yout_kernel(
    const float* __restrict__ M, const float* __restrict__ rj,
    const float* __restrict__ x,
    const float* __restrict__ ow, const float* __restrict__ ob,
    float* __restrict__ out)
{
    const int b = blockIdx.y, q = blockIdx.x;
    const int tx = threadIdx.x, ty = threadIdx.y, tid = ty * 16 + tx;

    // LDS: phase1 SA/SB [32][129] fp32 at [0,33024); then Zs u16[128][132]
    // at [0,33792) (overlaps dead SA/SB); OWs [32][129] fp32 at [33792,50304).
    __shared__ __align__(16) char smem[50304];
    float* SA  = (float*)smem;
    float* SB  = (float*)(smem + 16512);
    u16*   Zs  = (u16*)smem;
    float* OWs = (float*)(smem + 33792);

    float acc[8][8] = {};
    for (int t0 = 0; t0 < C_; t0 += 32) {
        for (int r = 0; r < 16; ++r) {          // M[j, t0+tk] -> SA[tk][j]
            int e = tid + 256 * r;
            int jj = e >> 5, tk = e & 31;
            SA[tk * 129 + jj] = M[(size_t)b * 32768 + (size_t)jj * 256 + t0 + tk];
        }
        for (int r = 0; r < 16; ++r) {          // X[t0+tk, 32c+q] -> SB[tk][c]
            int e = tid + 256 * r;
            int tk = e >> 7, cc = e & 127;
            SB[tk * 129 + cc] = x[((size_t)(b * C_ + t0 + tk)) * N_ + 32 * cc + q];
        }
        __syncthreads();
        for (int k = 0; k < 32; ++k) {
            float a[8], c[8];
            #pragma unroll
            for (int u = 0; u < 8; ++u) a[u] = SA[k * 129 + ty * 8 + u];
            #pragma unroll
            for (int v = 0; v < 8; ++v) c[v] = SB[k * 129 + tx * 8 + v];
            #pragma unroll
            for (int u = 0; u < 8; ++u)
                #pragma unroll
                for (int v = 0; v < 8; ++v) acc[u][v] += a[u] * c[v];
        }
        __syncthreads();
    }
    float rv[8];
    #pragma unroll
    for (int u = 0; u < 8; ++u) rv[u] = rj[b * 128 + ty * 8 + u];
    #pragma unroll
    for (int u = 0; u < 8; ++u)                 // Z[j][c] bf16 into LDS
        #pragma unroll
        for (int v = 0; v < 8; ++v)
            Zs[(ty * 8 + u) * 132 + tx * 8 + v] = f2bs(acc[u][v] + rv[u]);
    __syncthreads();

    for (int h = 0; h < 2; ++h) {               // o-halves [0,128), [128,256)
        float a2[8][8] = {};
        for (int c0 = 0; c0 < CI_; c0 += 32) {
            for (int r = 0; r < 16; ++r) {      // Ow[128h+oo, c0+ck] -> OWs[ck][oo]
                int e = tid + 256 * r;
                int oo = e >> 5, ck = e & 31;
                OWs[ck * 129 + oo] = ow[(128 * h + oo) * CI_ + c0 + ck];
            }
            __syncthreads();
            for (int k = 0; k < 32; ++k) {
                float a[8], z[8];
                #pragma unroll
                for (int u = 0; u < 8; ++u) a[u] = OWs[k * 129 + ty * 8 + u];
                #pragma unroll
                for (int v = 0; v < 8; ++v) z[v] = bs2f(Zs[(tx * 8 + v) * 132 + c0 + k]);
                #pragma unroll
                for (int u = 0; u < 8; ++u)
                    #pragma unroll
                    for (int v = 0; v < 8; ++v) a2[u][v] += a[u] * z[v];
            }
            __syncthreads();
        }
        #pragma unroll
        for (int u = 0; u < 8; ++u) {
            int o = 128 * h + ty * 8 + u;
            float bo = ob[o];
            #pragma unroll
            for (int v = 0; v < 8; ++v) {
                int p = 128 * q + tx * 8 + v;
                size_t idx = ((size_t)(b * C_ + o)) * N_ + p;
                out[idx] = a2[u][v] + bo + x[idx];
            }
        }
    }
}

extern "C" void kernel_launch(void* const* d_in, const int* in_sizes, int n_in,
                              void* d_out, int out_size, void* d_ws, size_t ws_size,
                              hipStream_t stream) {
    const float* x  = (const float*)d_in[0];
    const float* tw = (const float*)d_in[1];
    const float* tb = (const float*)d_in[2];
    const float* pw = (const float*)d_in[3];
    const float* pb = (const float*)d_in[4];
    const float* gw = (const float*)d_in[5];
    const float* gb = (const float*)d_in[6];
    const float* ow = (const float*)d_in[7];
    const float* ob = (const float*)d_in[8];
    float* out = (float*)d_out;

    // workspace (fp32, total 14,729,216 B ≈ 14.05 MB):
    //   G    [B,256,256] @ 0           ( 8,388,608)
    //   sx   [B,256]     @  8,388,608  (    32,768)
    //   A1/M [B,128,256] @  8,421,376  ( 4,194,304)  A1 consumed, reused as M
    //   fsm  [B,128,128] @ 12,615,680  ( 2,097,152)
    //   rj   [B,128]     @ 14,712,832  (    16,384)
    char* ws = (char*)d_ws;
    float* G   = (float*)(ws);
    float* sx  = (float*)(ws + 8388608ull);
    float* A1  = (float*)(ws + 8421376ull);
    float* fsm = (float*)(ws + 12615680ull);
    float* rj  = (float*)(ws + 14712832ull);

    dim3 blk(16, 16);
    hipLaunchKernelGGL(zero_kernel, dim3(2048), dim3(256), 0, stream, G);
    hipLaunchKernelGGL(sx_kernel, dim3(C_, B_), dim3(64), 0, stream, x, sx);
    hipLaunchKernelGGL(gram_kernel, dim3(2, 2, B_ * 4), blk, 0, stream, x, G);
    hipLaunchKernelGGL(a1_kernel, dim3(2, B_), blk, 0, stream, tw, G, A1);
    hipLaunchKernelGGL(f_kernel, dim3(B_), blk, 0, stream, A1, tw, tb, pw, pb, sx, fsm);
    hipLaunchKernelGGL(m_kernel, dim3(2, B_), blk, 0, stream, fsm, gw, gb, A1, rj);
    hipLaunchKernelGGL(yout_kernel, dim3(32, B_), blk, 0, stream, A1, rj, x, ow, ob, out);
}

// Round 4
// 952.750 us; speedup vs baseline: 1.4355x; 1.4355x over previous
//
#include <hip/hip_runtime.h>

#define B_ 32
#define C_ 256
#define CI_ 128
#define N_ 4096

typedef unsigned int u32;
typedef unsigned short u16;
typedef __attribute__((ext_vector_type(8))) short s8v;   // 8 bf16 (4 VGPR)
typedef __attribute__((ext_vector_type(4))) float f4v;   // 4 fp32 acc

__device__ __forceinline__ u16 f2bs(float f) {   // fp32 -> bf16 bits (RNE)
    union { float f; u32 u; } c; c.f = f;
    u32 u = c.u + 0x7FFFu + ((c.u >> 16) & 1u);
    return (u16)(u >> 16);
}
__device__ __forceinline__ float bs2f(u16 s) {   // bf16 bits -> fp32
    union { u32 u; float f; } c; c.u = ((u32)s) << 16; return c.f;
}
// split float -> (hi bf16, lo bf16) with x ~= hi + lo
__device__ __forceinline__ void split2(float x, u16& h, u16& l) {
    h = f2bs(x);
    l = f2bs(x - bs2f(h));
}

#define MFMA16(a, b, c) __builtin_amdgcn_mfma_f32_16x16x32_bf16((a), (b), (c), 0, 0, 0)

// ---------------------------------------------------------------------------
// K1: row sums sx[b,t] = sum_n X[b,t,n]. grid (C,B), block 64 (one wave).
// ---------------------------------------------------------------------------
__global__ __launch_bounds__(64) void sx_kernel(
    const float* __restrict__ x, float* __restrict__ sx)
{
    const int t = blockIdx.x, b = blockIdx.y, lane = threadIdx.x;
    const float4* row = (const float4*)(x + ((size_t)(b * C_ + t)) * N_);
    float s = 0.f;
    for (int k = lane; k < N_ / 4; k += 64) {
        float4 v = row[k];
        s += v.x + v.y + v.z + v.w;
    }
    #pragma unroll
    for (int off = 32; off > 0; off >>= 1) s += __shfl_down(s, off);
    if (lane == 0) sx[b * C_ + t] = s;
}

// ---------------------------------------------------------------------------
// K2: Gram G[b] = X_b · X_bᵀ via MFMA, hi/lo 3-pass (fp32-quality).
// grid (2 j-half, 2 i-half, B), block 256 (4 waves). Block = 128x128 out,
// full K=4096 (no atomics). Wave w: rows [w*32, w*32+32), all 128 cols.
// LDS: Ah/Al/Bh/Bl [128][40] u16 (BK=32, pad 8 -> 2-way bank alias = free).
// ---------------------------------------------------------------------------
__global__ __launch_bounds__(256) void gram_mfma(
    const float* __restrict__ x, float* __restrict__ G)
{
    const int b = blockIdx.z;
    const int i0 = blockIdx.y * 128, j0 = blockIdx.x * 128;
    const int tid = threadIdx.x;
    const int w = tid >> 6, l = tid & 63, lm = l & 15, lq = l >> 4;

    __shared__ u16 Ah[128 * 40], Al[128 * 40], Bh[128 * 40], Bl[128 * 40];

    f4v acc[2][8];
    #pragma unroll
    for (int mi = 0; mi < 2; ++mi)
        #pragma unroll
        for (int ni = 0; ni < 8; ++ni) acc[mi][ni] = (f4v){0.f, 0.f, 0.f, 0.f};

    const int srow = tid >> 3;          // 0..31
    const int sc4  = (tid & 7) * 4;     // 0,4,...,28

    for (int k0 = 0; k0 < N_; k0 += 32) {
        // ---- stage A (rows i0..i0+127) and B (rows j0..j0+127), cols k0..k0+31
        #pragma unroll
        for (int rr = 0; rr < 4; ++rr) {
            int row = rr * 32 + srow;
            float4 va = *(const float4*)(x + (((size_t)(b * C_ + i0 + row)) << 12) + k0 + sc4);
            float4 vb = *(const float4*)(x + (((size_t)(b * C_ + j0 + row)) << 12) + k0 + sc4);
            u16 h0, h1, h2, h3, l0, l1, l2, l3;
            split2(va.x, h0, l0); split2(va.y, h1, l1);
            split2(va.z, h2, l2); split2(va.w, h3, l3);
            *(uint2*)&Ah[row * 40 + sc4] = make_uint2((u32)h0 | ((u32)h1 << 16),
                                                      (u32)h2 | ((u32)h3 << 16));
            *(uint2*)&Al[row * 40 + sc4] = make_uint2((u32)l0 | ((u32)l1 << 16),
                                                      (u32)l2 | ((u32)l3 << 16));
            split2(vb.x, h0, l0); split2(vb.y, h1, l1);
            split2(vb.z, h2, l2); split2(vb.w, h3, l3);
            *(uint2*)&Bh[row * 40 + sc4] = make_uint2((u32)h0 | ((u32)h1 << 16),
                                                      (u32)h2 | ((u32)h3 << 16));
            *(uint2*)&Bl[row * 40 + sc4] = make_uint2((u32)l0 | ((u32)l1 << 16),
                                                      (u32)l2 | ((u32)l3 << 16));
        }
        __syncthreads();

        const int kofs = lq * 8;
        s8v ah[2], al2[2];
        #pragma unroll
        for (int mi = 0; mi < 2; ++mi) {
            int arow = w * 32 + mi * 16 + lm;
            ah[mi]  = *(const s8v*)&Ah[arow * 40 + kofs];
            al2[mi] = *(const s8v*)&Al[arow * 40 + kofs];
        }
        #pragma unroll
        for (int ni = 0; ni < 8; ++ni) {
            int brow = ni * 16 + lm;
            s8v bh = *(const s8v*)&Bh[brow * 40 + kofs];
            s8v bl = *(const s8v*)&Bl[brow * 40 + kofs];
            #pragma unroll
            for (int mi = 0; mi < 2; ++mi) {
                acc[mi][ni] = MFMA16(ah[mi],  bh, acc[mi][ni]);
                acc[mi][ni] = MFMA16(ah[mi],  bl, acc[mi][ni]);
                acc[mi][ni] = MFMA16(al2[mi], bh, acc[mi][ni]);
            }
        }
        __syncthreads();
    }
    // epilogue: D[row=(lq*4+r)][col=lm] per 16x16 tile
    #pragma unroll
    for (int mi = 0; mi < 2; ++mi)
        #pragma unroll
        for (int ni = 0; ni < 8; ++ni)
            #pragma unroll
            for (int r = 0; r < 4; ++r) {
                int gi = i0 + w * 32 + mi * 16 + lq * 4 + r;
                int gj = j0 + ni * 16 + lm;
                G[(size_t)b * 65536 + (size_t)gi * 256 + gj] = acc[mi][ni][r];
            }
}

// ---------------------------------------------------------------------------
// K3: A1[b] = Tw · G[b]  ([128,256] fp32). grid (2,B), block (16,16). VALU.
// ---------------------------------------------------------------------------
__global__ __launch_bounds__(256) void a1_kernel(
    const float* __restrict__ tw, const float* __restrict__ G,
    float* __restrict__ A1)
{
    const int b = blockIdx.y, u0 = blockIdx.x * 128;
    const int tx = threadIdx.x, ty = threadIdx.y, tid = ty * 16 + tx;
    __shared__ float Tws[32][129], Gs[32][129];
    float acc[8][8] = {};
    for (int t0 = 0; t0 < C_; t0 += 32) {
        for (int r = 0; r < 16; ++r) {
            int e = tid + 256 * r;
            int ii = e >> 5, tk = e & 31;
            Tws[tk][ii] = tw[ii * C_ + t0 + tk];
        }
        for (int r = 0; r < 16; ++r) {
            int e = tid + 256 * r;
            int tk = e >> 7, uu = e & 127;
            Gs[tk][uu] = G[(size_t)b * 65536 + (size_t)(t0 + tk) * 256 + u0 + uu];
        }
        __syncthreads();
        for (int k = 0; k < 32; ++k) {
            float a[8], c[8];
            #pragma unroll
            for (int u = 0; u < 8; ++u) a[u] = Tws[k][ty * 8 + u];
            #pragma unroll
            for (int v = 0; v < 8; ++v) c[v] = Gs[k][tx * 8 + v];
            #pragma unroll
            for (int u = 0; u < 8; ++u)
                #pragma unroll
                for (int v = 0; v < 8; ++v) acc[u][v] += a[u] * c[v];
        }
        __syncthreads();
    }
    #pragma unroll
    for (int u = 0; u < 8; ++u)
        #pragma unroll
        for (int v = 0; v < 8; ++v)
            A1[(size_t)b * 32768 + (size_t)(ty * 8 + u) * 256 + u0 + tx * 8 + v] = acc[u][v];
}

// ---------------------------------------------------------------------------
// K4: F = A1·Pwᵀ + t1·pbᵀ + tb·t2ᵀ + N·tb·pbᵀ, row-softmax -> fsm fp32.
// grid (B), block (16,16). VALU.
// ---------------------------------------------------------------------------
__global__ __launch_bounds__(256) void f_kernel(
    const float* __restrict__ A1,
    const float* __restrict__ tw, const float* __restrict__ tb,
    const float* __restrict__ pw, const float* __restrict__ pb,
    const float* __restrict__ sx, float* __restrict__ fsm)
{
    const int b = blockIdx.x;
    const int tx = threadIdx.x, ty = threadIdx.y, tid = ty * 16 + tx;
    __shared__ float sxs[256], t12[256];
    __shared__ float As[32][129], Ps[32][129];
    sxs[tid] = sx[b * 256 + tid];
    __syncthreads();
    {
        float s = 0.f;
        if (tid < 128) {
            for (int t = 0; t < 256; ++t) s += tw[tid * 256 + t] * sxs[t];
        } else {
            int j = tid - 128;
            for (int t = 0; t < 256; ++t) s += pw[j * 256 + t] * sxs[t];
        }
        t12[tid] = s;
    }
    float acc[8][8] = {};
    for (int u0 = 0; u0 < C_; u0 += 32) {
        for (int r = 0; r < 16; ++r) {
            int e = tid + 256 * r;
            int ii = e >> 5, uk = e & 31;
            As[uk][ii] = A1[(size_t)b * 32768 + (size_t)ii * 256 + u0 + uk];
            Ps[uk][ii] = pw[ii * 256 + u0 + uk];
        }
        __syncthreads();
        for (int k = 0; k < 32; ++k) {
            float a[8], c[8];
            #pragma unroll
            for (int u = 0; u < 8; ++u) a[u] = As[k][ty * 8 + u];
            #pragma unroll
            for (int v = 0; v < 8; ++v) c[v] = Ps[k][tx * 8 + v];
            #pragma unroll
            for (int u = 0; u < 8; ++u)
                #pragma unroll
                for (int v = 0; v < 8; ++v) acc[u][v] += a[u] * c[v];
        }
        __syncthreads();
    }
    float tbv[8], pbv[8], t2v[8];
    #pragma unroll
    for (int u = 0; u < 8; ++u) tbv[u] = tb[ty * 8 + u];
    #pragma unroll
    for (int v = 0; v < 8; ++v) {
        int j = tx * 8 + v;
        pbv[v] = pb[j];
        t2v[v] = t12[128 + j];
    }
    #pragma unroll
    for (int u = 0; u < 8; ++u) {
        const int i = ty * 8 + u;
        float t1i = t12[i];
        float row[8];
        #pragma unroll
        for (int v = 0; v < 8; ++v)
            row[v] = acc[u][v] + t1i * pbv[v] + tbv[u] * (t2v[v] + 4096.0f * pbv[v]);
        float m = row[0];
        #pragma unroll
        for (int v = 1; v < 8; ++v) m = fmaxf(m, row[v]);
        m = fmaxf(m, __shfl_xor(m, 1));
        m = fmaxf(m, __shfl_xor(m, 2));
        m = fmaxf(m, __shfl_xor(m, 4));
        m = fmaxf(m, __shfl_xor(m, 8));
        float s = 0.f;
        #pragma unroll
        for (int v = 0; v < 8; ++v) s += __expf(row[v] - m);
        s += __shfl_xor(s, 1);
        s += __shfl_xor(s, 2);
        s += __shfl_xor(s, 4);
        s += __shfl_xor(s, 8);
        float inv = 1.0f / s;
        #pragma unroll
        for (int v = 0; v < 8; ++v)
            fsm[(size_t)b * 16384 + (size_t)i * 128 + tx * 8 + v] = __expf(row[v] - m) * inv;
    }
}

// ---------------------------------------------------------------------------
// K5: Mh[b] = bf16(f_smᵀ · Gw) ([128 j,256 t]); rj[b,j] = f_smᵀ·gb.
// grid (2,B), block (16,16). VALU (small).
// ---------------------------------------------------------------------------
__global__ __launch_bounds__(256) void m_kernel(
    const float* __restrict__ fsm, const float* __restrict__ gw,
    const float* __restrict__ gb,
    u16* __restrict__ Mh, float* __restrict__ rj)
{
    const int b = blockIdx.y, t0 = blockIdx.x * 128;
    const int tx = threadIdx.x, ty = threadIdx.y, tid = ty * 16 + tx;
    __shared__ float Fs[32][129], Gs[32][129];
    float acc[8][8] = {};
    for (int i0 = 0; i0 < CI_; i0 += 32) {
        for (int r = 0; r < 16; ++r) {
            int e = tid + 256 * r;
            int ik = e >> 7, jj = e & 127;
            Fs[ik][jj] = fsm[(size_t)b * 16384 + (size_t)(i0 + ik) * 128 + jj];
            Gs[ik][jj] = gw[(i0 + ik) * 256 + t0 + jj];
        }
        __syncthreads();
        for (int k = 0; k < 32; ++k) {
            float a[8], c[8];
            #pragma unroll
            for (int u = 0; u < 8; ++u) a[u] = Fs[k][ty * 8 + u];
            #pragma unroll
            for (int v = 0; v < 8; ++v) c[v] = Gs[k][tx * 8 + v];
            #pragma unroll
            for (int u = 0; u < 8; ++u)
                #pragma unroll
                for (int v = 0; v < 8; ++v) acc[u][v] += a[u] * c[v];
        }
        __syncthreads();
    }
    #pragma unroll
    for (int u = 0; u < 8; ++u)
        #pragma unroll
        for (int v = 0; v < 8; ++v)
            Mh[(size_t)b * 32768 + (size_t)(ty * 8 + u) * 256 + t0 + tx * 8 + v] = f2bs(acc[u][v]);
    if (blockIdx.x == 0 && tid < 128) {
        float s = 0.f;
        for (int i = 0; i < 128; ++i)
            s += fsm[(size_t)b * 16384 + (size_t)i * 128 + tid] * gb[i];
        rj[b * 128 + tid] = s;
    }
}

// ---------------------------------------------------------------------------
// K5b: Owh = bf16(ow), [256,128]. grid (32), block 256, 4 elems/thread.
// ---------------------------------------------------------------------------
__global__ __launch_bounds__(256) void owh_kernel(
    const float* __restrict__ ow, u16* __restrict__ Owh)
{
    int i = (blockIdx.x * 256 + threadIdx.x) * 4;
    float4 v = *(const float4*)(ow + i);
    u16 a = f2bs(v.x), b = f2bs(v.y), c = f2bs(v.z), d = f2bs(v.w);
    *(uint2*)&Owh[i] = make_uint2((u32)a | ((u32)b << 16), (u32)c | ((u32)d << 16));
}

// ---------------------------------------------------------------------------
// K6 (MFMA fused y + out conv + residual). Block (q,b), 256 threads, 4 waves.
// Phase 1: Z[s=128][c=128] = sum_t Mh[s,t]·X[t,32c+q] + rj[s]  (bf16 in LDS)
//   wave w: s-rows [w*32,w*32+32), all c. A from global Mh; B staged in Xs.
// Phase 2: out[o, 128q+s] = sum_c Owh[o,c]·Z[s][c] + ob[o] + x[...]
//   wave w: o-rows [w*64,w*64+64), all s. A from global Owh; B = Zs.
// ---------------------------------------------------------------------------
__global__ __launch_bounds__(256) void yout_mfma(
    const u16* __restrict__ Mh, const float* __restrict__ rj,
    const float* __restrict__ x,
    const u16* __restrict__ Owh, const float* __restrict__ ob,
    float* __restrict__ out)
{
    const int q = blockIdx.x, b = blockIdx.y;
    const int tid = threadIdx.x;
    const int w = tid >> 6, l = tid & 63, lm = l & 15, lq = l >> 4;

    __shared__ u16 Xs[128 * 40];     // [c][tt], stride 40 (pad 8)
    __shared__ u16 Zs[128 * 136];    // [s][c],  stride 136 (pad 8)

    // ---------------- phase 1 ----------------
    f4v acc1[2][8];
    #pragma unroll
    for (int mi = 0; mi < 2; ++mi)
        #pragma unroll
        for (int ni = 0; ni < 8; ++ni) acc1[mi][ni] = (f4v){0.f, 0.f, 0.f, 0.f};

    const int sc = tid & 127, stp = tid >> 7;   // staging: c, t-half
    for (int t0 = 0; t0 < C_; t0 += 32) {
        u16 tmp[16];
        #pragma unroll
        for (int i = 0; i < 16; ++i) {
            int tt = stp * 16 + i;
            tmp[i] = f2bs(x[(((size_t)(b * C_ + t0 + tt)) << 12) + 32 * sc + q]);
        }
        *(uint4*)&Xs[sc * 40 + stp * 16]     = *(const uint4*)&tmp[0];
        *(uint4*)&Xs[sc * 40 + stp * 16 + 8] = *(const uint4*)&tmp[8];
        __syncthreads();

        s8v af[2];
        #pragma unroll
        for (int mi = 0; mi < 2; ++mi)
            af[mi] = *(const s8v*)(Mh + (size_t)b * 32768
                                   + (size_t)(w * 32 + mi * 16 + lm) * 256 + t0 + lq * 8);
        #pragma unroll
        for (int ni = 0; ni < 8; ++ni) {
            s8v bf = *(const s8v*)&Xs[(ni * 16 + lm) * 40 + lq * 8];
            acc1[0][ni] = MFMA16(af[0], bf, acc1[0][ni]);
            acc1[1][ni] = MFMA16(af[1], bf, acc1[1][ni]);
        }
        __syncthreads();
    }
    // epilogue 1: Z[s][c] = acc + rj[s]
    #pragma unroll
    for (int mi = 0; mi < 2; ++mi) {
        float rjv[4];
        #pragma unroll
        for (int r = 0; r < 4; ++r)
            rjv[r] = rj[b * 128 + w * 32 + mi * 16 + lq * 4 + r];
        #pragma unroll
        for (int ni = 0; ni < 8; ++ni)
            #pragma unroll
            for (int r = 0; r < 4; ++r) {
                int s = w * 32 + mi * 16 + lq * 4 + r;
                Zs[s * 136 + ni * 16 + lm] = f2bs(acc1[mi][ni][r] + rjv[r]);
            }
    }
    __syncthreads();

    // ---------------- phase 2 ----------------
    f4v acc2[4][8];
    #pragma unroll
    for (int mi = 0; mi < 4; ++mi)
        #pragma unroll
        for (int ni = 0; ni < 8; ++ni) acc2[mi][ni] = (f4v){0.f, 0.f, 0.f, 0.f};

    for (int kc = 0; kc < 4; ++kc) {
        s8v af[4];
        #pragma unroll
        for (int mi = 0; mi < 4; ++mi)
            af[mi] = *(const s8v*)(Owh + (size_t)(w * 64 + mi * 16 + lm) * 128
                                   + kc * 32 + lq * 8);
        #pragma unroll
        for (int ni = 0; ni < 8; ++ni) {
            s8v bf = *(const s8v*)&Zs[(ni * 16 + lm) * 136 + kc * 32 + lq * 8];
            #pragma unroll
            for (int mi = 0; mi < 4; ++mi)
                acc2[mi][ni] = MFMA16(af[mi], bf, acc2[mi][ni]);
        }
    }
    // epilogue 2: out = acc + ob + x
    #pragma unroll
    for (int mi = 0; mi < 4; ++mi) {
        #pragma unroll
        for (int r = 0; r < 4; ++r) {
            int o = w * 64 + mi * 16 + lq * 4 + r;
            float bo = ob[o];
            #pragma unroll
            for (int ni = 0; ni < 8; ++ni) {
                int p = 128 * q + ni * 16 + lm;
                size_t idx = (((size_t)(b * C_ + o)) << 12) + p;
                out[idx] = acc2[mi][ni][r] + bo + x[idx];
            }
        }
    }
}

extern "C" void kernel_launch(void* const* d_in, const int* in_sizes, int n_in,
                              void* d_out, int out_size, void* d_ws, size_t ws_size,
                              hipStream_t stream) {
    const float* x  = (const float*)d_in[0];
    const float* tw = (const float*)d_in[1];
    const float* tb = (const float*)d_in[2];
    const float* pw = (const float*)d_in[3];
    const float* pb = (const float*)d_in[4];
    const float* gw = (const float*)d_in[5];
    const float* gb = (const float*)d_in[6];
    const float* ow = (const float*)d_in[7];
    const float* ob = (const float*)d_in[8];
    float* out = (float*)d_out;

    // workspace (total 16,891,904 B ~= 16.1 MB):
    //   G   fp32 [B,256,256] @ 0           ( 8,388,608)
    //   sx  fp32 [B,256]     @  8,388,608  (    32,768)
    //   A1  fp32 [B,128,256] @  8,421,376  ( 4,194,304)
    //   fsm fp32 [B,128,128] @ 12,615,680  ( 2,097,152)
    //   rj  fp32 [B,128]     @ 14,712,832  (    16,384)
    //   Mh  bf16 [B,128,256] @ 14,729,216  ( 2,097,152)
    //   Owh bf16 [256,128]   @ 16,826,368  (    65,536)
    char* ws = (char*)d_ws;
    float* G   = (float*)(ws);
    float* sx  = (float*)(ws + 8388608ull);
    float* A1  = (float*)(ws + 8421376ull);
    float* fsm = (float*)(ws + 12615680ull);
    float* rj  = (float*)(ws + 14712832ull);
    u16*   Mh  = (u16*)(ws + 14729216ull);
    u16*   Owh = (u16*)(ws + 16826368ull);

    dim3 blk2(16, 16);
    hipLaunchKernelGGL(sx_kernel, dim3(C_, B_), dim3(64), 0, stream, x, sx);
    hipLaunchKernelGGL(gram_mfma, dim3(2, 2, B_), dim3(256), 0, stream, x, G);
    hipLaunchKernelGGL(a1_kernel, dim3(2, B_), blk2, 0, stream, tw, G, A1);
    hipLaunchKernelGGL(f_kernel, dim3(B_), blk2, 0, stream, A1, tw, tb, pw, pb, sx, fsm);
    hipLaunchKernelGGL(m_kernel, dim3(2, B_), blk2, 0, stream, fsm, gw, gb, Mh, rj);
    hipLaunchKernelGGL(owh_kernel, dim3(32), dim3(256), 0, stream, ow, Owh);
    hipLaunchKernelGGL(yout_mfma, dim3(32, B_), dim3(256), 0, stream, Mh, rj, x, Owh, ob, out);
}